// Round 9
// baseline (194.421 us; speedup 1.0000x reference)
//
#include <hip/hip_runtime.h>
#include <stdint.h>

#define T_LEN 2048

typedef __attribute__((ext_vector_type(8))) short bf16x8;
typedef __attribute__((ext_vector_type(16))) float f32x16;

// RNE fp32 pair -> packed bf16x2 (inputs finite normals)
static __device__ __forceinline__ unsigned pack_bf16(float a, float b) {
    unsigned ua = __float_as_uint(a);
    unsigned ub = __float_as_uint(b);
    ua = (ua + 0x7fffu + ((ua >> 16) & 1u)) >> 16;
    ub = (ub + 0x7fffu + ((ub >> 16) & 1u));
    return (ua & 0xffffu) | (ub & 0xffff0000u);
}

// async global->LDS DMA, 16 B/lane: LDS dest = wave-uniform base + lane*16
static __device__ __forceinline__ void async16(const void* g, void* l) {
    __builtin_amdgcn_global_load_lds(
        (const __attribute__((address_space(1))) unsigned int*)g,
        (__attribute__((address_space(3))) unsigned int*)l, 16, 0, 0);
}

// 2^x on the transcendental pipe (scores carry log2e folded in from prepack)
static __device__ __forceinline__ float fexp2(float x) {
#if __has_builtin(__builtin_amdgcn_exp2f)
    return __builtin_amdgcn_exp2f(x);
#else
    float r; asm("v_exp_f32 %0, %1" : "=v"(r) : "v"(x)); return r;
#endif
}

// v_permlane32_swap_b32 a, b (in-place, inline asm; HW-verified R6):
//   a_new = {a.lo, b.lo}, b_new = {a.hi, b.hi}  (a.hi <-> b.lo)
static __device__ __forceinline__ void swap32(unsigned& a, unsigned& b) {
    asm("v_permlane32_swap_b32 %0, %1" : "+v"(a), "+v"(b));
}

// ---------------------------------------------------------------------------
// Prepack (R6/R7 verbatim, 128B swizzled rows):
//   Q: ws+0     bf16 [head][t][swz c]  rows 128B, scaled 0.125*log2(e)
//   K: ws+8MB   bf16 [head][s][swz c]  rows 128B
//   V: ws+16MB  bf16 [head][sTile(64)][c][swz s] rows 128B
// ---------------------------------------------------------------------------
__global__ __launch_bounds__(256)
void prepack(const float* __restrict__ qkv, char* __restrict__ ws)
{
    __shared__ float tile[64 * 130];
    const int tid = threadIdx.x;
    const int b = blockIdx.x;

    if (b < 1024) {                       // ---- Q / K transpose
        const int isK  = b >> 9;
        const int bb   = b & 511;
        const int head = bb >> 4, chunk = bb & 15;
        const float* src = qkv + (size_t)head * 192 * T_LEN
                               + (size_t)(isK ? 64 : 0) * T_LEN;
        const int t0g = chunk * 128;
        const float scale = isK ? 1.0f : 0.18033688f;
#pragma unroll
        for (int i = 0; i < 8; ++i) {
            int p = i * 256 + tid;
            int t4 = p & 31, c = p >> 5;
            float4 v = *(const float4*)(src + (size_t)c * T_LEN + t0g + 4 * t4);
            int a = c * 130 + 4 * t4;
            *(float2*)&tile[a]     = make_float2(v.x, v.y);
            *(float2*)&tile[a + 2] = make_float2(v.z, v.w);
        }
        __syncthreads();
        unsigned* dst = (unsigned*)ws + (size_t)isK * 2097152
                      + (size_t)head * 65536 + (size_t)t0g * 32;
#pragma unroll
        for (int i = 0; i < 16; ++i) {
            int cp = tid & 31, t = i * 8 + (tid >> 5);
            float f0 = tile[(2 * cp) * 130 + t] * scale;
            float f1 = tile[(2 * cp + 1) * 130 + t] * scale;
            dst[t * 32 + (((cp >> 2) ^ (t & 7)) << 2) + (cp & 3)] = pack_bf16(f0, f1);
        }
    } else {                              // ---- V pass-through (swizzle only)
        const int b3 = b - 1024;
        const int head = b3 >> 5, st = b3 & 31;
        const float* src = qkv + (size_t)head * 192 * T_LEN + (size_t)128 * T_LEN;
        const int s0 = st * 64;
        unsigned* dst = (unsigned*)(ws + 16777216) + (size_t)b3 * 2048;
#pragma unroll
        for (int i = 0; i < 8; ++i) {
            int p = i * 256 + tid;
            int s2 = p & 31, c = p >> 5;
            float2 v = *(const float2*)(src + (size_t)c * T_LEN + s0 + 2 * s2);
            dst[c * 32 + (((s2 >> 2) ^ (c & 7)) << 2) + (s2 & 3)] = pack_bf16(v.x, v.y);
        }
    }
}

// ---------------------------------------------------------------------------
// Main: R7 verbatim (best passing, 49.0us). 8 waves x 512 thr, LDS dbuf + DMA,
// wave (wt2, wsx) owns 32t x 32s per iteration.
// ---------------------------------------------------------------------------
__global__ __launch_bounds__(512, 4)
void attn_fwd(const char* __restrict__ ws, float* __restrict__ out)
{
    __shared__ char smem[50176];
    const int tid  = threadIdx.x;
    const int wave = tid >> 6, lane = tid & 63;
    const int l31  = lane & 31, h = lane >> 5;
    const int wt2  = wave & 3;
    const int wsx  = wave >> 2;
    const int head = blockIdx.x & 31, tb = blockIdx.x >> 5;
    const int swq  = l31 & 7;

    const char* qsrc = ws + (size_t)head * 262144 + (size_t)tb * 16384;
    const char* ksrc = ws + 8388608  + (size_t)head * 262144;
    const char* vsrc = ws + 16777216 + (size_t)head * 262144;

    char*  Qs = smem;
    char*  Ks = smem + 16384;
    char*  Vs = smem + 32768;
    float* Lb = (float*)(smem + 49152);
    float* Ob = (float*)smem;

#pragma unroll
    for (int n = 0; n < 2; ++n) {
        int ch = wave * 2 + n;
        async16(qsrc + ch * 1024 + lane * 16, Qs + ch * 1024);
    }
    async16(ksrc + wave * 1024 + lane * 16, Ks + wave * 1024);
    async16(vsrc + wave * 1024 + lane * 16, Vs + wave * 1024);
    __syncthreads();

    bf16x8 qf[4];
#pragma unroll
    for (int kb = 0; kb < 4; ++kb)
        qf[kb] = *(const bf16x8*)(Qs + (wt2 * 32 + l31) * 128
                                  + (((kb * 2 + h) ^ swq) << 4));

    f32x16 acc[2];
#pragma unroll
    for (int ct = 0; ct < 2; ++ct)
#pragma unroll
        for (int r = 0; r < 16; ++r) acc[ct][r] = 0.f;
    float lp = 0.f;

    for (int i = 0; i < 32; ++i) {
        const int cur = i & 1, nxt = cur ^ 1;
        if (i) __syncthreads();
        if (i < 31) {
            async16(ksrc + (i + 1) * 8192 + wave * 1024 + lane * 16,
                    Ks + nxt * 8192 + wave * 1024);
            async16(vsrc + (i + 1) * 8192 + wave * 1024 + lane * 16,
                    Vs + nxt * 8192 + wave * 1024);
        }

        const char* KsB = Ks + cur * 8192;
        const char* VsB = Vs + cur * 8192;
        f32x16 sc;
#pragma unroll
        for (int r = 0; r < 16; ++r) sc[r] = 0.f;
        const int krow = (wsx * 32 + l31) * 128;
#pragma unroll
        for (int kb = 0; kb < 4; ++kb) {
            bf16x8 kf = *(const bf16x8*)(KsB + krow + (((kb * 2 + h) ^ swq) << 4));
            sc = __builtin_amdgcn_mfma_f32_32x32x16_bf16(kf, qf[kb], sc, 0, 0, 0);
        }

        union P8 { unsigned u[8]; bf16x8 v[2]; };
        P8 P;
#pragma unroll
        for (int d = 0; d < 8; ++d) {
            unsigned a0 = __float_as_uint(fexp2(sc[2 * d]))     & 0xffff0000u;
            unsigned a1 = __float_as_uint(fexp2(sc[2 * d + 1])) & 0xffff0000u;
            lp += __uint_as_float(a0) + __uint_as_float(a1);
            P.u[d] = __builtin_amdgcn_perm(a1, a0, 0x07060302u);
        }
        swap32(P.u[0], P.u[2]); swap32(P.u[1], P.u[3]);
        swap32(P.u[4], P.u[6]); swap32(P.u[5], P.u[7]);

#pragma unroll
        for (int kb2 = 0; kb2 < 2; ++kb2) {
            const bf16x8 pfv = kb2 ? P.v[1] : P.v[0];
#pragma unroll
            for (int ct = 0; ct < 2; ++ct) {
                bf16x8 vf = *(const bf16x8*)(VsB + (ct * 32 + l31) * 128
                              + (((wsx * 4 + kb2 * 2 + h) ^ swq) << 4));
                acc[ct] = __builtin_amdgcn_mfma_f32_32x32x16_bf16(vf, pfv, acc[ct], 0, 0, 0);
            }
        }
    }

    __syncthreads();

    float lt = lp + __shfl_xor(lp, 32);
    if (h == 0) Lb[wsx * 128 + wt2 * 32 + l31] = lt;

    if (wsx == 1) {
#pragma unroll
        for (int ct = 0; ct < 2; ++ct)
#pragma unroll
            for (int r = 0; r < 16; ++r) {
                int c = ct * 32 + (r & 3) + 8 * (r >> 2) + 4 * h;
                Ob[c * 128 + wt2 * 32 + l31] = acc[ct][r];
            }
    }
    __syncthreads();

    if (wsx == 0) {
        const float li = 1.0f / (Lb[wt2 * 32 + l31] + Lb[128 + wt2 * 32 + l31]);
#pragma unroll
        for (int ct = 0; ct < 2; ++ct)
#pragma unroll
            for (int r = 0; r < 16; ++r) {
                int c = ct * 32 + (r & 3) + 8 * (r >> 2) + 4 * h;
                float v = acc[ct][r] + Ob[c * 128 + wt2 * 32 + l31];
                out[((size_t)head * 64 + c) * T_LEN + tb * 128 + wt2 * 32 + l31]
                    = v * li;
            }
    }
}

// ---------------------------------------------------------------------------
// ABLATION clones (diagnostic, this round only). Identical structure to
// attn_fwd; write NOTHING to global (values kept live via empty asm, rule #17
// keep-alive — no DCE, no scratch races).
//   MODE 1 (noEXP):    fexp2(x) -> x. Isolates the 16 v_exp trans ops/iter.
//   MODE 2 (skeleton): softmax/pack/lp/swap removed; sc kept live via asm;
//                      PV fed from resident qf regs (same MFMA count/shape).
//                      Isolates the loads+MFMA+barrier schedule floor.
// Pre-committed reads: fwd-A1 = exp cost; A1-A2 = pack/lp/swap cost;
// A2 = skeleton floor.
// ---------------------------------------------------------------------------
template<int MODE>
__global__ __launch_bounds__(512, 4)
void attn_abl(const char* __restrict__ ws)
{
    __shared__ char smem[50176];
    const int tid  = threadIdx.x;
    const int wave = tid >> 6, lane = tid & 63;
    const int l31  = lane & 31, h = lane >> 5;
    const int wt2  = wave & 3;
    const int wsx  = wave >> 2;
    const int head = blockIdx.x & 31, tb = blockIdx.x >> 5;
    const int swq  = l31 & 7;

    const char* qsrc = ws + (size_t)head * 262144 + (size_t)tb * 16384;
    const char* ksrc = ws + 8388608  + (size_t)head * 262144;
    const char* vsrc = ws + 16777216 + (size_t)head * 262144;

    char*  Qs = smem;
    char*  Ks = smem + 16384;
    char*  Vs = smem + 32768;
    float* Lb = (float*)(smem + 49152);
    float* Ob = (float*)smem;

#pragma unroll
    for (int n = 0; n < 2; ++n) {
        int ch = wave * 2 + n;
        async16(qsrc + ch * 1024 + lane * 16, Qs + ch * 1024);
    }
    async16(ksrc + wave * 1024 + lane * 16, Ks + wave * 1024);
    async16(vsrc + wave * 1024 + lane * 16, Vs + wave * 1024);
    __syncthreads();

    bf16x8 qf[4];
#pragma unroll
    for (int kb = 0; kb < 4; ++kb)
        qf[kb] = *(const bf16x8*)(Qs + (wt2 * 32 + l31) * 128
                                  + (((kb * 2 + h) ^ swq) << 4));

    f32x16 acc[2];
#pragma unroll
    for (int ct = 0; ct < 2; ++ct)
#pragma unroll
        for (int r = 0; r < 16; ++r) acc[ct][r] = 0.f;
    float lp = 0.f;

    for (int i = 0; i < 32; ++i) {
        const int cur = i & 1, nxt = cur ^ 1;
        if (i) __syncthreads();
        if (i < 31) {
            async16(ksrc + (i + 1) * 8192 + wave * 1024 + lane * 16,
                    Ks + nxt * 8192 + wave * 1024);
            async16(vsrc + (i + 1) * 8192 + wave * 1024 + lane * 16,
                    Vs + nxt * 8192 + wave * 1024);
        }

        const char* KsB = Ks + cur * 8192;
        const char* VsB = Vs + cur * 8192;
        f32x16 sc;
#pragma unroll
        for (int r = 0; r < 16; ++r) sc[r] = 0.f;
        const int krow = (wsx * 32 + l31) * 128;
#pragma unroll
        for (int kb = 0; kb < 4; ++kb) {
            bf16x8 kf = *(const bf16x8*)(KsB + krow + (((kb * 2 + h) ^ swq) << 4));
            sc = __builtin_amdgcn_mfma_f32_32x32x16_bf16(kf, qf[kb], sc, 0, 0, 0);
        }

        union P8 { unsigned u[8]; bf16x8 v[2]; };
        P8 P;
        if constexpr (MODE == 1) {
            // noEXP: identical softmax minus the 16 v_exp
#pragma unroll
            for (int d = 0; d < 8; ++d) {
                unsigned a0 = __float_as_uint(sc[2 * d])     & 0xffff0000u;
                unsigned a1 = __float_as_uint(sc[2 * d + 1]) & 0xffff0000u;
                lp += __uint_as_float(a0) + __uint_as_float(a1);
                P.u[d] = __builtin_amdgcn_perm(a1, a0, 0x07060302u);
            }
            swap32(P.u[0], P.u[2]); swap32(P.u[1], P.u[3]);
            swap32(P.u[4], P.u[6]); swap32(P.u[5], P.u[7]);
        } else {
            // skeleton: keep sc live (QK not DCE'd), no softmax at all
#pragma unroll
            for (int r = 0; r < 16; ++r) asm volatile("" :: "v"(sc[r]));
            P.v[0] = qf[0]; P.v[1] = qf[2];   // register-resident operands
        }

#pragma unroll
        for (int kb2 = 0; kb2 < 2; ++kb2) {
            const bf16x8 pfv = kb2 ? P.v[1] : P.v[0];
#pragma unroll
            for (int ct = 0; ct < 2; ++ct) {
                bf16x8 vf = *(const bf16x8*)(VsB + (ct * 32 + l31) * 128
                              + (((wsx * 4 + kb2 * 2 + h) ^ swq) << 4));
                acc[ct] = __builtin_amdgcn_mfma_f32_32x32x16_bf16(vf, pfv, acc[ct], 0, 0, 0);
            }
        }
    }

    __syncthreads();

    float lt = lp + __shfl_xor(lp, 32);
    if (h == 0) Lb[wsx * 128 + wt2 * 32 + l31] = lt;

    if (wsx == 1) {
#pragma unroll
        for (int ct = 0; ct < 2; ++ct)
#pragma unroll
            for (int r = 0; r < 16; ++r) {
                int c = ct * 32 + (r & 3) + 8 * (r >> 2) + 4 * h;
                Ob[c * 128 + wt2 * 32 + l31] = acc[ct][r];
            }
    }
    __syncthreads();

    if (wsx == 0) {
        const float li = 1.0f / (Lb[wt2 * 32 + l31] + Lb[128 + wt2 * 32 + l31]);
#pragma unroll
        for (int ct = 0; ct < 2; ++ct)
#pragma unroll
            for (int r = 0; r < 16; ++r) {
                int c = ct * 32 + (r & 3) + 8 * (r >> 2) + 4 * h;
                float v = acc[ct][r] + Ob[c * 128 + wt2 * 32 + l31];
                asm volatile("" :: "v"(v * li));   // keep-alive, no store
            }
    }
}

extern "C" void kernel_launch(void* const* d_in, const int* in_sizes, int n_in,
                              void* d_out, int out_size, void* d_ws, size_t ws_size,
                              hipStream_t stream) {
    const float* qkv = (const float*)d_in[0];
    float* out = (float*)d_out;
    char* ws = (char*)d_ws;   // 24 MB
    hipLaunchKernelGGL(prepack, dim3(2048), dim3(256), 0, stream, qkv, ws);
    hipLaunchKernelGGL(attn_fwd, dim3(512), dim3(512), 0, stream, ws, out);
    // ---- diagnostic ablations (write nothing; this round only) ----
    hipLaunchKernelGGL((attn_abl<1>), dim3(512), dim3(512), 0, stream, ws);
    hipLaunchKernelGGL((attn_abl<2>), dim3(512), dim3(512), 0, stream, ws);
}

// Round 12
// 129.182 us; speedup vs baseline: 1.5050x; 1.5050x over previous
//
#include <hip/hip_runtime.h>
#include <stdint.h>

#define T_LEN 2048

typedef __attribute__((ext_vector_type(8))) short bf16x8;
typedef __attribute__((ext_vector_type(16))) float f32x16;

// RNE fp32 pair -> packed bf16x2 (inputs finite normals)
static __device__ __forceinline__ unsigned pack_bf16(float a, float b) {
    unsigned ua = __float_as_uint(a);
    unsigned ub = __float_as_uint(b);
    ua = (ua + 0x7fffu + ((ua >> 16) & 1u)) >> 16;
    ub = (ub + 0x7fffu + ((ub >> 16) & 1u));
    return (ua & 0xffffu) | (ub & 0xffff0000u);
}

// async global->LDS DMA, 16 B/lane: LDS dest = wave-uniform base + lane*16
static __device__ __forceinline__ void async16(const void* g, void* l) {
    __builtin_amdgcn_global_load_lds(
        (const __attribute__((address_space(1))) unsigned int*)g,
        (__attribute__((address_space(3))) unsigned int*)l, 16, 0, 0);
}

// 2^x on the transcendental pipe (scores carry log2e folded in from prepack)
static __device__ __forceinline__ float fexp2(float x) {
#if __has_builtin(__builtin_amdgcn_exp2f)
    return __builtin_amdgcn_exp2f(x);
#else
    float r; asm("v_exp_f32 %0, %1" : "=v"(r) : "v"(x)); return r;
#endif
}

// v_permlane32_swap_b32 a, b (in-place, inline asm; HW-verified R6):
//   a_new = {a.lo, b.lo}, b_new = {a.hi, b.hi}  (a.hi <-> b.lo)
static __device__ __forceinline__ void swap32(unsigned& a, unsigned& b) {
    asm("v_permlane32_swap_b32 %0, %1" : "+v"(a), "+v"(b));
}

// ---------------------------------------------------------------------------
// Prepack (R6/R7 verbatim, 128B swizzled rows):
//   Q: ws+0     bf16 [head][t][swz c]  rows 128B, scaled 0.125*log2(e)
//   K: ws+8MB   bf16 [head][s][swz c]  rows 128B
//   V: ws+16MB  bf16 [head][sTile(64)][c][swz s] rows 128B
// ---------------------------------------------------------------------------
__global__ __launch_bounds__(256)
void prepack(const float* __restrict__ qkv, char* __restrict__ ws)
{
    __shared__ float tile[64 * 130];
    const int tid = threadIdx.x;
    const int b = blockIdx.x;

    if (b < 1024) {                       // ---- Q / K transpose
        const int isK  = b >> 9;
        const int bb   = b & 511;
        const int head = bb >> 4, chunk = bb & 15;
        const float* src = qkv + (size_t)head * 192 * T_LEN
                               + (size_t)(isK ? 64 : 0) * T_LEN;
        const int t0g = chunk * 128;
        const float scale = isK ? 1.0f : 0.18033688f;
#pragma unroll
        for (int i = 0; i < 8; ++i) {
            int p = i * 256 + tid;
            int t4 = p & 31, c = p >> 5;
            float4 v = *(const float4*)(src + (size_t)c * T_LEN + t0g + 4 * t4);
            int a = c * 130 + 4 * t4;
            *(float2*)&tile[a]     = make_float2(v.x, v.y);
            *(float2*)&tile[a + 2] = make_float2(v.z, v.w);
        }
        __syncthreads();
        unsigned* dst = (unsigned*)ws + (size_t)isK * 2097152
                      + (size_t)head * 65536 + (size_t)t0g * 32;
#pragma unroll
        for (int i = 0; i < 16; ++i) {
            int cp = tid & 31, t = i * 8 + (tid >> 5);
            float f0 = tile[(2 * cp) * 130 + t] * scale;
            float f1 = tile[(2 * cp + 1) * 130 + t] * scale;
            dst[t * 32 + (((cp >> 2) ^ (t & 7)) << 2) + (cp & 3)] = pack_bf16(f0, f1);
        }
    } else {                              // ---- V pass-through (swizzle only)
        const int b3 = b - 1024;
        const int head = b3 >> 5, st = b3 & 31;
        const float* src = qkv + (size_t)head * 192 * T_LEN + (size_t)128 * T_LEN;
        const int s0 = st * 64;
        unsigned* dst = (unsigned*)(ws + 16777216) + (size_t)b3 * 2048;
#pragma unroll
        for (int i = 0; i < 8; ++i) {
            int p = i * 256 + tid;
            int s2 = p & 31, c = p >> 5;
            float2 v = *(const float2*)(src + (size_t)c * T_LEN + s0 + 2 * s2);
            dst[c * 32 + (((s2 >> 2) ^ (c & 7)) << 2) + (s2 & 3)] = pack_bf16(v.x, v.y);
        }
    }
}

// ---------------------------------------------------------------------------
// Main: R7 structure verbatim (8 waves x 512 thr, LDS dbuf + DMA, wave
// (wt2,wsx) owns 32t x 32s). R12 = R7 + two provably-safe deltas:
//   1. 4-way lp accumulator split (fp32 reassociation of a positive sum;
//      same change-class as R3's passing 2-way split) — shortens the serial
//      v_add dependency chain 16 -> 4.
//   2. s_setprio(1) wrapped around the MFMA clusters only (T5, m191
//      attn-verified; pure scheduling hint) — MFMA-phase waves outrank
//      softmax-phase waves on the SIMD.
// ---------------------------------------------------------------------------
__global__ __launch_bounds__(512, 4)
void attn_fwd(const char* __restrict__ ws, float* __restrict__ out)
{
    __shared__ char smem[50176];
    const int tid  = threadIdx.x;
    const int wave = tid >> 6, lane = tid & 63;
    const int l31  = lane & 31, h = lane >> 5;
    const int wt2  = wave & 3;
    const int wsx  = wave >> 2;
    const int head = blockIdx.x & 31, tb = blockIdx.x >> 5;
    const int swq  = l31 & 7;

    const char* qsrc = ws + (size_t)head * 262144 + (size_t)tb * 16384;
    const char* ksrc = ws + 8388608  + (size_t)head * 262144;
    const char* vsrc = ws + 16777216 + (size_t)head * 262144;

    char*  Qs = smem;
    char*  Ks = smem + 16384;
    char*  Vs = smem + 32768;
    float* Lb = (float*)(smem + 49152);
    float* Ob = (float*)smem;

#pragma unroll
    for (int n = 0; n < 2; ++n) {
        int ch = wave * 2 + n;
        async16(qsrc + ch * 1024 + lane * 16, Qs + ch * 1024);
    }
    async16(ksrc + wave * 1024 + lane * 16, Ks + wave * 1024);
    async16(vsrc + wave * 1024 + lane * 16, Vs + wave * 1024);
    __syncthreads();

    bf16x8 qf[4];
#pragma unroll
    for (int kb = 0; kb < 4; ++kb)
        qf[kb] = *(const bf16x8*)(Qs + (wt2 * 32 + l31) * 128
                                  + (((kb * 2 + h) ^ swq) << 4));

    f32x16 acc[2];
#pragma unroll
    for (int ct = 0; ct < 2; ++ct)
#pragma unroll
        for (int r = 0; r < 16; ++r) acc[ct][r] = 0.f;
    float lp4[4] = {0.f, 0.f, 0.f, 0.f};   // 4-way split (static idx, unrolled)

    for (int i = 0; i < 32; ++i) {
        const int cur = i & 1, nxt = cur ^ 1;
        if (i) __syncthreads();
        if (i < 31) {
            async16(ksrc + (i + 1) * 8192 + wave * 1024 + lane * 16,
                    Ks + nxt * 8192 + wave * 1024);
            async16(vsrc + (i + 1) * 8192 + wave * 1024 + lane * 16,
                    Vs + nxt * 8192 + wave * 1024);
        }

        const char* KsB = Ks + cur * 8192;
        const char* VsB = Vs + cur * 8192;
        f32x16 sc;
#pragma unroll
        for (int r = 0; r < 16; ++r) sc[r] = 0.f;
        const int krow = (wsx * 32 + l31) * 128;

        __builtin_amdgcn_s_setprio(1);
#pragma unroll
        for (int kb = 0; kb < 4; ++kb) {
            bf16x8 kf = *(const bf16x8*)(KsB + krow + (((kb * 2 + h) ^ swq) << 4));
            sc = __builtin_amdgcn_mfma_f32_32x32x16_bf16(kf, qf[kb], sc, 0, 0, 0);
        }
        __builtin_amdgcn_s_setprio(0);

        // ---- softmax (R7-verbatim): raw 2^x + bf16 truncation pack;
        // lp in 4 independent accumulators (chain 16 -> 4)
        union P8 { unsigned u[8]; bf16x8 v[2]; };
        P8 P;
#pragma unroll
        for (int d = 0; d < 8; ++d) {
            unsigned a0 = __float_as_uint(fexp2(sc[2 * d]))     & 0xffff0000u;
            unsigned a1 = __float_as_uint(fexp2(sc[2 * d + 1])) & 0xffff0000u;
            lp4[d & 3] += __uint_as_float(a0) + __uint_as_float(a1);
            P.u[d] = __builtin_amdgcn_perm(a1, a0, 0x07060302u);
        }
        swap32(P.u[0], P.u[2]); swap32(P.u[1], P.u[3]);
        swap32(P.u[4], P.u[6]); swap32(P.u[5], P.u[7]);

        // ---- PV: O^T[c][t] += V[c][s] * P[t][s]
        __builtin_amdgcn_s_setprio(1);
#pragma unroll
        for (int kb2 = 0; kb2 < 2; ++kb2) {
            const bf16x8 pfv = kb2 ? P.v[1] : P.v[0];
#pragma unroll
            for (int ct = 0; ct < 2; ++ct) {
                bf16x8 vf = *(const bf16x8*)(VsB + (ct * 32 + l31) * 128
                              + (((wsx * 4 + kb2 * 2 + h) ^ swq) << 4));
                acc[ct] = __builtin_amdgcn_mfma_f32_32x32x16_bf16(vf, pfv, acc[ct], 0, 0, 0);
            }
        }
        __builtin_amdgcn_s_setprio(0);
    }

    __syncthreads();

    const float lp = (lp4[0] + lp4[1]) + (lp4[2] + lp4[3]);
    float lt = lp + __shfl_xor(lp, 32);
    if (h == 0) Lb[wsx * 128 + wt2 * 32 + l31] = lt;

    if (wsx == 1) {
#pragma unroll
        for (int ct = 0; ct < 2; ++ct)
#pragma unroll
            for (int r = 0; r < 16; ++r) {
                int c = ct * 32 + (r & 3) + 8 * (r >> 2) + 4 * h;
                Ob[c * 128 + wt2 * 32 + l31] = acc[ct][r];
            }
    }
    __syncthreads();

    if (wsx == 0) {
        const float li = 1.0f / (Lb[wt2 * 32 + l31] + Lb[128 + wt2 * 32 + l31]);
#pragma unroll
        for (int ct = 0; ct < 2; ++ct)
#pragma unroll
            for (int r = 0; r < 16; ++r) {
                int c = ct * 32 + (r & 3) + 8 * (r >> 2) + 4 * h;
                float v = acc[ct][r] + Ob[c * 128 + wt2 * 32 + l31];
                out[((size_t)head * 64 + c) * T_LEN + tb * 128 + wt2 * 32 + l31]
                    = v * li;
            }
    }
}

extern "C" void kernel_launch(void* const* d_in, const int* in_sizes, int n_in,
                              void* d_out, int out_size, void* d_ws, size_t ws_size,
                              hipStream_t stream) {
    const float* qkv = (const float*)d_in[0];
    float* out = (float*)d_out;
    char* ws = (char*)d_ws;   // 24 MB
    hipLaunchKernelGGL(prepack, dim3(2048), dim3(256), 0, stream, qkv, ws);
    hipLaunchKernelGGL(attn_fwd, dim3(512), dim3(512), 0, stream, ws, out);
}

// Round 13
// 127.449 us; speedup vs baseline: 1.5255x; 1.0136x over previous
//
#include <hip/hip_runtime.h>
#include <stdint.h>

#define T_LEN 2048

typedef __attribute__((ext_vector_type(8))) short bf16x8;
typedef __attribute__((ext_vector_type(16))) float f32x16;

// RNE fp32 pair -> packed bf16x2 (inputs finite normals)
static __device__ __forceinline__ unsigned pack_bf16(float a, float b) {
    unsigned ua = __float_as_uint(a);
    unsigned ub = __float_as_uint(b);
    ua = (ua + 0x7fffu + ((ua >> 16) & 1u)) >> 16;
    ub = (ub + 0x7fffu + ((ub >> 16) & 1u));
    return (ua & 0xffffu) | (ub & 0xffff0000u);
}

// async global->LDS DMA, 16 B/lane: LDS dest = wave-uniform base + lane*16
static __device__ __forceinline__ void async16(const void* g, void* l) {
    __builtin_amdgcn_global_load_lds(
        (const __attribute__((address_space(1))) unsigned int*)g,
        (__attribute__((address_space(3))) unsigned int*)l, 16, 0, 0);
}

// 2^x on the transcendental pipe (scores carry log2e folded in from prepack)
static __device__ __forceinline__ float fexp2(float x) {
#if __has_builtin(__builtin_amdgcn_exp2f)
    return __builtin_amdgcn_exp2f(x);
#else
    float r; asm("v_exp_f32 %0, %1" : "=v"(r) : "v"(x)); return r;
#endif
}

// v_permlane32_swap_b32 a, b (in-place, inline asm; HW-verified R6):
//   a_new = {a.lo, b.lo}, b_new = {a.hi, b.hi}  (a.hi <-> b.lo)
static __device__ __forceinline__ void swap32(unsigned& a, unsigned& b) {
    asm("v_permlane32_swap_b32 %0, %1" : "+v"(a), "+v"(b));
}

// ---------------------------------------------------------------------------
// Prepack (R6/R7 layout verbatim; V pass upgraded to float4 loads):
//   Q: ws+0     bf16 [head][t][swz c]  rows 128B, scaled 0.125*log2(e)
//   K: ws+8MB   bf16 [head][s][swz c]  rows 128B
//   V: ws+16MB  bf16 [head][sTile(64)][c][swz s] rows 128B
// ---------------------------------------------------------------------------
__global__ __launch_bounds__(256)
void prepack(const float* __restrict__ qkv, char* __restrict__ ws)
{
    __shared__ float tile[64 * 130];
    const int tid = threadIdx.x;
    const int b = blockIdx.x;

    if (b < 1024) {                       // ---- Q / K transpose
        const int isK  = b >> 9;
        const int bb   = b & 511;
        const int head = bb >> 4, chunk = bb & 15;
        const float* src = qkv + (size_t)head * 192 * T_LEN
                               + (size_t)(isK ? 64 : 0) * T_LEN;
        const int t0g = chunk * 128;
        const float scale = isK ? 1.0f : 0.18033688f;
#pragma unroll
        for (int i = 0; i < 8; ++i) {
            int p = i * 256 + tid;
            int t4 = p & 31, c = p >> 5;
            float4 v = *(const float4*)(src + (size_t)c * T_LEN + t0g + 4 * t4);
            int a = c * 130 + 4 * t4;
            *(float2*)&tile[a]     = make_float2(v.x, v.y);
            *(float2*)&tile[a + 2] = make_float2(v.z, v.w);
        }
        __syncthreads();
        unsigned* dst = (unsigned*)ws + (size_t)isK * 2097152
                      + (size_t)head * 65536 + (size_t)t0g * 32;
#pragma unroll
        for (int i = 0; i < 16; ++i) {
            int cp = tid & 31, t = i * 8 + (tid >> 5);
            float f0 = tile[(2 * cp) * 130 + t] * scale;
            float f1 = tile[(2 * cp + 1) * 130 + t] * scale;
            dst[t * 32 + (((cp >> 2) ^ (t & 7)) << 2) + (cp & 3)] = pack_bf16(f0, f1);
        }
    } else {                              // ---- V pass-through (swizzle only)
        const int b3 = b - 1024;
        const int head = b3 >> 5, st = b3 & 31;
        const float* src = qkv + (size_t)head * 192 * T_LEN + (size_t)128 * T_LEN;
        const int s0 = st * 64;
        unsigned* dst = (unsigned*)(ws + 16777216) + (size_t)b3 * 2048;
        // float4 loads: each thread handles a 4-float span (two packed words)
#pragma unroll
        for (int i = 0; i < 4; ++i) {
            int p = i * 256 + tid;          // 1024 spans of 4 floats
            int s4 = p & 15, c = p >> 4;    // s4: 16 spans cover 64 s; c: 0..63
            float4 v = *(const float4*)(src + (size_t)c * T_LEN + s0 + 4 * s4);
            int s2a = 2 * s4, s2b = 2 * s4 + 1;
            dst[c * 32 + (((s2a >> 2) ^ (c & 7)) << 2) + (s2a & 3)] = pack_bf16(v.x, v.y);
            dst[c * 32 + (((s2b >> 2) ^ (c & 7)) << 2) + (s2b & 3)] = pack_bf16(v.z, v.w);
        }
    }
}

// ---------------------------------------------------------------------------
// Main: R12 structure verbatim (8 waves x 512 thr, LDS dbuf + DMA, wave
// (wt2,wsx) owns 32t x 32s; 4-way lp split; setprio around MFMA clusters).
// R13 delta: persistent zero-C (zf) for QK^T's first MFMA — removes the 16
// v_mov/iter re-zeroing of sc. Semantically exact (never-written zero vector).
// ---------------------------------------------------------------------------
__global__ __launch_bounds__(512, 4)
void attn_fwd(const char* __restrict__ ws, float* __restrict__ out)
{
    __shared__ char smem[50176];
    const int tid  = threadIdx.x;
    const int wave = tid >> 6, lane = tid & 63;
    const int l31  = lane & 31, h = lane >> 5;
    const int wt2  = wave & 3;
    const int wsx  = wave >> 2;
    const int head = blockIdx.x & 31, tb = blockIdx.x >> 5;
    const int swq  = l31 & 7;

    const char* qsrc = ws + (size_t)head * 262144 + (size_t)tb * 16384;
    const char* ksrc = ws + 8388608  + (size_t)head * 262144;
    const char* vsrc = ws + 16777216 + (size_t)head * 262144;

    char*  Qs = smem;
    char*  Ks = smem + 16384;
    char*  Vs = smem + 32768;
    float* Lb = (float*)(smem + 49152);
    float* Ob = (float*)smem;

#pragma unroll
    for (int n = 0; n < 2; ++n) {
        int ch = wave * 2 + n;
        async16(qsrc + ch * 1024 + lane * 16, Qs + ch * 1024);
    }
    async16(ksrc + wave * 1024 + lane * 16, Ks + wave * 1024);
    async16(vsrc + wave * 1024 + lane * 16, Vs + wave * 1024);
    __syncthreads();

    bf16x8 qf[4];
#pragma unroll
    for (int kb = 0; kb < 4; ++kb)
        qf[kb] = *(const bf16x8*)(Qs + (wt2 * 32 + l31) * 128
                                  + (((kb * 2 + h) ^ swq) << 4));

    f32x16 acc[2];
#pragma unroll
    for (int ct = 0; ct < 2; ++ct)
#pragma unroll
        for (int r = 0; r < 16; ++r) acc[ct][r] = 0.f;

    f32x16 zf;                          // persistent zero C-operand, never written
#pragma unroll
    for (int r = 0; r < 16; ++r) zf[r] = 0.f;

    float lp4[4] = {0.f, 0.f, 0.f, 0.f};

    for (int i = 0; i < 32; ++i) {
        const int cur = i & 1, nxt = cur ^ 1;
        if (i) __syncthreads();
        if (i < 31) {
            async16(ksrc + (i + 1) * 8192 + wave * 1024 + lane * 16,
                    Ks + nxt * 8192 + wave * 1024);
            async16(vsrc + (i + 1) * 8192 + wave * 1024 + lane * 16,
                    Vs + nxt * 8192 + wave * 1024);
        }

        const char* KsB = Ks + cur * 8192;
        const char* VsB = Vs + cur * 8192;
        const int krow = (wsx * 32 + l31) * 128;

        __builtin_amdgcn_s_setprio(1);
        bf16x8 kf0 = *(const bf16x8*)(KsB + krow + ((h ^ swq) << 4));
        f32x16 sc = __builtin_amdgcn_mfma_f32_32x32x16_bf16(kf0, qf[0], zf, 0, 0, 0);
#pragma unroll
        for (int kb = 1; kb < 4; ++kb) {
            bf16x8 kf = *(const bf16x8*)(KsB + krow + (((kb * 2 + h) ^ swq) << 4));
            sc = __builtin_amdgcn_mfma_f32_32x32x16_bf16(kf, qf[kb], sc, 0, 0, 0);
        }
        __builtin_amdgcn_s_setprio(0);

        // ---- softmax: raw 2^x + bf16 truncation pack; lp sums the EXACT
        // truncated weights (4 independent chains)
        union P8 { unsigned u[8]; bf16x8 v[2]; };
        P8 P;
#pragma unroll
        for (int d = 0; d < 8; ++d) {
            unsigned a0 = __float_as_uint(fexp2(sc[2 * d]))     & 0xffff0000u;
            unsigned a1 = __float_as_uint(fexp2(sc[2 * d + 1])) & 0xffff0000u;
            lp4[d & 3] += __uint_as_float(a0) + __uint_as_float(a1);
            P.u[d] = __builtin_amdgcn_perm(a1, a0, 0x07060302u);
        }
        swap32(P.u[0], P.u[2]); swap32(P.u[1], P.u[3]);
        swap32(P.u[4], P.u[6]); swap32(P.u[5], P.u[7]);

        // ---- PV: O^T[c][t] += V[c][s] * P[t][s]
        __builtin_amdgcn_s_setprio(1);
#pragma unroll
        for (int kb2 = 0; kb2 < 2; ++kb2) {
            const bf16x8 pfv = kb2 ? P.v[1] : P.v[0];
#pragma unroll
            for (int ct = 0; ct < 2; ++ct) {
                bf16x8 vf = *(const bf16x8*)(VsB + (ct * 32 + l31) * 128
                              + (((wsx * 4 + kb2 * 2 + h) ^ swq) << 4));
                acc[ct] = __builtin_amdgcn_mfma_f32_32x32x16_bf16(vf, pfv, acc[ct], 0, 0, 0);
            }
        }
        __builtin_amdgcn_s_setprio(0);
    }

    __syncthreads();

    const float lp = (lp4[0] + lp4[1]) + (lp4[2] + lp4[3]);
    float lt = lp + __shfl_xor(lp, 32);
    if (h == 0) Lb[wsx * 128 + wt2 * 32 + l31] = lt;

    if (wsx == 1) {
#pragma unroll
        for (int ct = 0; ct < 2; ++ct)
#pragma unroll
            for (int r = 0; r < 16; ++r) {
                int c = ct * 32 + (r & 3) + 8 * (r >> 2) + 4 * h;
                Ob[c * 128 + wt2 * 32 + l31] = acc[ct][r];
            }
    }
    __syncthreads();

    if (wsx == 0) {
        const float li = 1.0f / (Lb[wt2 * 32 + l31] + Lb[128 + wt2 * 32 + l31]);
#pragma unroll
        for (int ct = 0; ct < 2; ++ct)
#pragma unroll
            for (int r = 0; r < 16; ++r) {
                int c = ct * 32 + (r & 3) + 8 * (r >> 2) + 4 * h;
                float v = acc[ct][r] + Ob[c * 128 + wt2 * 32 + l31];
                out[((size_t)head * 64 + c) * T_LEN + tb * 128 + wt2 * 32 + l31]
                    = v * li;
            }
    }
}

extern "C" void kernel_launch(void* const* d_in, const int* in_sizes, int n_in,
                              void* d_out, int out_size, void* d_ws, size_t ws_size,
                              hipStream_t stream) {
    const float* qkv = (const float*)d_in[0];
    float* out = (float*)d_out;
    char* ws = (char*)d_ws;   // 24 MB
    hipLaunchKernelGGL(prepack, dim3(2048), dim3(256), 0, stream, qkv, ws);
    hipLaunchKernelGGL(attn_fwd, dim3(512), dim3(512), 0, stream, ws, out);
}

// Round 15
// 125.485 us; speedup vs baseline: 1.5494x; 1.0157x over previous
//
#include <hip/hip_runtime.h>
#include <stdint.h>

#define T_LEN 2048

typedef __attribute__((ext_vector_type(8))) short bf16x8;
typedef __attribute__((ext_vector_type(16))) float f32x16;
typedef __attribute__((ext_vector_type(2))) __bf16 bf16x2v;

// RNE fp32 pair -> packed bf16x2 (inputs finite normals)
static __device__ __forceinline__ unsigned pack_bf16(float a, float b) {
    unsigned ua = __float_as_uint(a);
    unsigned ub = __float_as_uint(b);
    ua = (ua + 0x7fffu + ((ua >> 16) & 1u)) >> 16;
    ub = (ub + 0x7fffu + ((ub >> 16) & 1u));
    return (ua & 0xffffu) | (ub & 0xffff0000u);
}

// async global->LDS DMA, 16 B/lane: LDS dest = wave-uniform base + lane*16
static __device__ __forceinline__ void async16(const void* g, void* l) {
    __builtin_amdgcn_global_load_lds(
        (const __attribute__((address_space(1))) unsigned int*)g,
        (__attribute__((address_space(3))) unsigned int*)l, 16, 0, 0);
}

// 2^x on the transcendental pipe (scores carry log2e folded in from prepack)
static __device__ __forceinline__ float fexp2(float x) {
#if __has_builtin(__builtin_amdgcn_exp2f)
    return __builtin_amdgcn_exp2f(x);
#else
    float r; asm("v_exp_f32 %0, %1" : "=v"(r) : "v"(x)); return r;
#endif
}

// v_permlane32_swap_b32 a, b (in-place, inline asm; HW-verified R6):
//   a_new = {a.lo, b.lo}, b_new = {a.hi, b.hi}  (a.hi <-> b.lo)
static __device__ __forceinline__ void swap32(unsigned& a, unsigned& b) {
    asm("v_permlane32_swap_b32 %0, %1" : "+v"(a), "+v"(b));
}

// lp accumulate from a packed bf16x2 word: returns c + lo + hi (exact: bf16
// values * 1.0 are exact f32 products). ORDER-INSENSITIVE (both B elems are
// 1.0) -> no operand-layout risk. Fallback is cost-equal to the R13 path.
static __device__ __forceinline__ float lp_acc(unsigned p, float c) {
#if __has_builtin(__builtin_amdgcn_fdot2_f32_bf16)
    bf16x2v a = __builtin_bit_cast(bf16x2v, p);
    bf16x2v one; one[0] = (__bf16)1.0f; one[1] = (__bf16)1.0f;
    return __builtin_amdgcn_fdot2_f32_bf16(a, one, c, false);
#else
    float t0 = __uint_as_float(p << 16);
    float t1 = __uint_as_float(p & 0xffff0000u);
    return c + t0 + t1;
#endif
}

// ---------------------------------------------------------------------------
// Prepack (R13 verbatim):
//   Q: ws+0     bf16 [head][t][swz c]  rows 128B, scaled 0.125*log2(e)
//   K: ws+8MB   bf16 [head][s][swz c]  rows 128B
//   V: ws+16MB  bf16 [head][sTile(64)][c][swz s] rows 128B
// ---------------------------------------------------------------------------
__global__ __launch_bounds__(256)
void prepack(const float* __restrict__ qkv, char* __restrict__ ws)
{
    __shared__ float tile[64 * 130];
    const int tid = threadIdx.x;
    const int b = blockIdx.x;

    if (b < 1024) {                       // ---- Q / K transpose
        const int isK  = b >> 9;
        const int bb   = b & 511;
        const int head = bb >> 4, chunk = bb & 15;
        const float* src = qkv + (size_t)head * 192 * T_LEN
                               + (size_t)(isK ? 64 : 0) * T_LEN;
        const int t0g = chunk * 128;
        const float scale = isK ? 1.0f : 0.18033688f;
#pragma unroll
        for (int i = 0; i < 8; ++i) {
            int p = i * 256 + tid;
            int t4 = p & 31, c = p >> 5;
            float4 v = *(const float4*)(src + (size_t)c * T_LEN + t0g + 4 * t4);
            int a = c * 130 + 4 * t4;
            *(float2*)&tile[a]     = make_float2(v.x, v.y);
            *(float2*)&tile[a + 2] = make_float2(v.z, v.w);
        }
        __syncthreads();
        unsigned* dst = (unsigned*)ws + (size_t)isK * 2097152
                      + (size_t)head * 65536 + (size_t)t0g * 32;
#pragma unroll
        for (int i = 0; i < 16; ++i) {
            int cp = tid & 31, t = i * 8 + (tid >> 5);
            float f0 = tile[(2 * cp) * 130 + t] * scale;
            float f1 = tile[(2 * cp + 1) * 130 + t] * scale;
            dst[t * 32 + (((cp >> 2) ^ (t & 7)) << 2) + (cp & 3)] = pack_bf16(f0, f1);
        }
    } else {                              // ---- V pass-through (swizzle only)
        const int b3 = b - 1024;
        const int head = b3 >> 5, st = b3 & 31;
        const float* src = qkv + (size_t)head * 192 * T_LEN + (size_t)128 * T_LEN;
        const int s0 = st * 64;
        unsigned* dst = (unsigned*)(ws + 16777216) + (size_t)b3 * 2048;
#pragma unroll
        for (int i = 0; i < 4; ++i) {
            int p = i * 256 + tid;
            int s4 = p & 15, c = p >> 4;
            float4 v = *(const float4*)(src + (size_t)c * T_LEN + s0 + 4 * s4);
            int s2a = 2 * s4, s2b = 2 * s4 + 1;
            dst[c * 32 + (((s2a >> 2) ^ (c & 7)) << 2) + (s2a & 3)] = pack_bf16(v.x, v.y);
            dst[c * 32 + (((s2b >> 2) ^ (c & 7)) << 2) + (s2b & 3)] = pack_bf16(v.z, v.w);
        }
    }
}

// ---------------------------------------------------------------------------
// Main: R13 structure verbatim (8 waves x 512 thr, LDS dbuf + DMA, wave
// (wt2,wsx) owns 32t x 32s; zf zero-C; setprio around MFMA; 4-way lp split).
// R14 delta (softmax block only; resubmitted unchanged after infra failure):
//   - the two & 0xffff0000 masks are DROPPED (v_perm sel 0x07060302 reads
//     only bytes 2,3 of each source -> masks were dead for the pack)
//   - lp accumulated from the PACKED word via v_dot2_f32_bf16 with B=(1,1):
//     exact sum of the truncated weights, one op replaces 2 and + 2 add
// Net: -24 VALU ops/thread/iter. Math identical to R13 (reassociation only).
// ---------------------------------------------------------------------------
__global__ __launch_bounds__(512, 4)
void attn_fwd(const char* __restrict__ ws, float* __restrict__ out)
{
    __shared__ char smem[50176];
    const int tid  = threadIdx.x;
    const int wave = tid >> 6, lane = tid & 63;
    const int l31  = lane & 31, h = lane >> 5;
    const int wt2  = wave & 3;
    const int wsx  = wave >> 2;
    const int head = blockIdx.x & 31, tb = blockIdx.x >> 5;
    const int swq  = l31 & 7;

    const char* qsrc = ws + (size_t)head * 262144 + (size_t)tb * 16384;
    const char* ksrc = ws + 8388608  + (size_t)head * 262144;
    const char* vsrc = ws + 16777216 + (size_t)head * 262144;

    char*  Qs = smem;
    char*  Ks = smem + 16384;
    char*  Vs = smem + 32768;
    float* Lb = (float*)(smem + 49152);
    float* Ob = (float*)smem;

#pragma unroll
    for (int n = 0; n < 2; ++n) {
        int ch = wave * 2 + n;
        async16(qsrc + ch * 1024 + lane * 16, Qs + ch * 1024);
    }
    async16(ksrc + wave * 1024 + lane * 16, Ks + wave * 1024);
    async16(vsrc + wave * 1024 + lane * 16, Vs + wave * 1024);
    __syncthreads();

    bf16x8 qf[4];
#pragma unroll
    for (int kb = 0; kb < 4; ++kb)
        qf[kb] = *(const bf16x8*)(Qs + (wt2 * 32 + l31) * 128
                                  + (((kb * 2 + h) ^ swq) << 4));

    f32x16 acc[2];
#pragma unroll
    for (int ct = 0; ct < 2; ++ct)
#pragma unroll
        for (int r = 0; r < 16; ++r) acc[ct][r] = 0.f;

    f32x16 zf;                          // persistent zero C-operand, never written
#pragma unroll
    for (int r = 0; r < 16; ++r) zf[r] = 0.f;

    float lp4[4] = {0.f, 0.f, 0.f, 0.f};

    for (int i = 0; i < 32; ++i) {
        const int cur = i & 1, nxt = cur ^ 1;
        if (i) __syncthreads();
        if (i < 31) {
            async16(ksrc + (i + 1) * 8192 + wave * 1024 + lane * 16,
                    Ks + nxt * 8192 + wave * 1024);
            async16(vsrc + (i + 1) * 8192 + wave * 1024 + lane * 16,
                    Vs + nxt * 8192 + wave * 1024);
        }

        const char* KsB = Ks + cur * 8192;
        const char* VsB = Vs + cur * 8192;
        const int krow = (wsx * 32 + l31) * 128;

        __builtin_amdgcn_s_setprio(1);
        bf16x8 kf0 = *(const bf16x8*)(KsB + krow + ((h ^ swq) << 4));
        f32x16 sc = __builtin_amdgcn_mfma_f32_32x32x16_bf16(kf0, qf[0], zf, 0, 0, 0);
#pragma unroll
        for (int kb = 1; kb < 4; ++kb) {
            bf16x8 kf = *(const bf16x8*)(KsB + krow + (((kb * 2 + h) ^ swq) << 4));
            sc = __builtin_amdgcn_mfma_f32_32x32x16_bf16(kf, qf[kb], sc, 0, 0, 0);
        }
        __builtin_amdgcn_s_setprio(0);

        // ---- softmax: raw 2^x -> perm pack (reads only hi bytes; no masks)
        // -> lp from the packed (truncated) weights via dot2
        union P8 { unsigned u[8]; bf16x8 v[2]; };
        P8 P;
#pragma unroll
        for (int d = 0; d < 8; ++d) {
            unsigned a0 = __float_as_uint(fexp2(sc[2 * d]));
            unsigned a1 = __float_as_uint(fexp2(sc[2 * d + 1]));
            P.u[d] = __builtin_amdgcn_perm(a1, a0, 0x07060302u);
            lp4[d & 3] = lp_acc(P.u[d], lp4[d & 3]);
        }
        swap32(P.u[0], P.u[2]); swap32(P.u[1], P.u[3]);
        swap32(P.u[4], P.u[6]); swap32(P.u[5], P.u[7]);

        // ---- PV: O^T[c][t] += V[c][s] * P[t][s]
        __builtin_amdgcn_s_setprio(1);
#pragma unroll
        for (int kb2 = 0; kb2 < 2; ++kb2) {
            const bf16x8 pfv = kb2 ? P.v[1] : P.v[0];
#pragma unroll
            for (int ct = 0; ct < 2; ++ct) {
                bf16x8 vf = *(const bf16x8*)(VsB + (ct * 32 + l31) * 128
                              + (((wsx * 4 + kb2 * 2 + h) ^ swq) << 4));
                acc[ct] = __builtin_amdgcn_mfma_f32_32x32x16_bf16(vf, pfv, acc[ct], 0, 0, 0);
            }
        }
        __builtin_amdgcn_s_setprio(0);
    }

    __syncthreads();

    const float lp = (lp4[0] + lp4[1]) + (lp4[2] + lp4[3]);
    float lt = lp + __shfl_xor(lp, 32);
    if (h == 0) Lb[wsx * 128 + wt2 * 32 + l31] = lt;

    if (wsx == 1) {
#pragma unroll
        for (int ct = 0; ct < 2; ++ct)
#pragma unroll
            for (int r = 0; r < 16; ++r) {
                int c = ct * 32 + (r & 3) + 8 * (r >> 2) + 4 * h;
                Ob[c * 128 + wt2 * 32 + l31] = acc[ct][r];
            }
    }
    __syncthreads();

    if (wsx == 0) {
        const float li = 1.0f / (Lb[wt2 * 32 + l31] + Lb[128 + wt2 * 32 + l31]);
#pragma unroll
        for (int ct = 0; ct < 2; ++ct)
#pragma unroll
            for (int r = 0; r < 16; ++r) {
                int c = ct * 32 + (r & 3) + 8 * (r >> 2) + 4 * h;
                float v = acc[ct][r] + Ob[c * 128 + wt2 * 32 + l31];
                out[((size_t)head * 64 + c) * T_LEN + tb * 128 + wt2 * 32 + l31]
                    = v * li;
            }
    }
}

extern "C" void kernel_launch(void* const* d_in, const int* in_sizes, int n_in,
                              void* d_out, int out_size, void* d_ws, size_t ws_size,
                              hipStream_t stream) {
    const float* qkv = (const float*)d_in[0];
    float* out = (float*)d_out;
    char* ws = (char*)d_ws;   // 24 MB
    hipLaunchKernelGGL(prepack, dim3(2048), dim3(256), 0, stream, qkv, ws);
    hipLaunchKernelGGL(attn_fwd, dim3(512), dim3(512), 0, stream, ws, out);
}